// Round 7
// baseline (287.750 us; speedup 1.0000x reference)
//
#include <hip/hip_runtime.h>
#include <math.h>

#define NROWS 500000
#define NGRP  50000
#define NEG   0.2f
#define GPB   16          // groups per bias-block (50000/16 = 3125 exactly)
#define NCHG  3125        // bias-blocks
#define NCHR  7813        // 64-row windows (7812*64+32 = 500000)

typedef __attribute__((ext_vector_type(8))) short bf16x8;   // 8 bf16 = 4 VGPRs
typedef __attribute__((ext_vector_type(4))) float f32x4;    // MFMA C/D
typedef unsigned int uint32;

__device__ __forceinline__ float leaky(float h) { return fmaxf(h, NEG * h); }
__device__ __forceinline__ unsigned short f2bf(float v) {   // RNE (k0 only)
    uint32 u = __float_as_uint(v);
    u += 0x7FFFu + ((u >> 16) & 1u);
    return (unsigned short)(u >> 16);
}
__device__ __forceinline__ float bf2f(unsigned short h) {
    return __uint_as_float((uint32)h << 16);
}
// HW packed f32->bf16 (RNE): 1 VALU op converts+packs 2 values.
__device__ __forceinline__ uint32 pkbf(float a, float b) {
    uint32 r;
    asm("v_cvt_pk_bf16_f32 %0, %1, %2" : "=v"(r) : "v"(a), "v"(b));
    return r;
}
__device__ __forceinline__ float4 min4(float4 a, float4 b) {
    return float4{fminf(a.x,b.x), fminf(a.y,b.y), fminf(a.z,b.z), fminf(a.w,b.w)};
}
__device__ __forceinline__ float4 max4(float4 a, float4 b) {
    return float4{fmaxf(a.x,b.x), fmaxf(a.y,b.y), fmaxf(a.z,b.z), fmaxf(a.w,b.w)};
}

// ---------------------------------------------------------------------------
// K0: pack Wsum = W1a+W1b+W1c and W2 into bf16 MFMA B-fragment-major layout:
//   frag[((ks*64 + n)*4 + q)*8 + j] = W[ks*32 + q*8 + j][n]
// Also pack W1bc (w1 rows 64..191, K=128) as a bf16 hi/lo pair for the
// ~fp32-accurate bias MFMA (drop lo*lo).
__global__ void k0_frag(const float* __restrict__ w1, const float* __restrict__ w2,
                        unsigned short* __restrict__ wsf, unsigned short* __restrict__ w2f,
                        unsigned short* __restrict__ wbh, unsigned short* __restrict__ wbl) {
    int r = blockIdx.x * 256 + threadIdx.x;
    if (r >= 8192) return;
    int j = r & 7, q = (r >> 3) & 3, n = (r >> 5) & 63;
    int k = (r >> 11) * 32 + q * 8 + j;          // 0..127
    if (r < 4096) {                              // k 0..63: layer-1/2 frags
        float ws = w1[k * 64 + n] + w1[4096 + k * 64 + n] + w1[8192 + k * 64 + n];
        wsf[r] = f2bf(ws);
        w2f[r] = f2bf(w2[k * 64 + n]);
    }
    float v = w1[(64 + k) * 64 + n];             // W1b (k<64) / W1c (k>=64)
    unsigned short h = f2bf(v);
    wbh[r] = h;
    wbl[r] = f2bf(v - bf2f(h));
}

// ---------------------------------------------------------------------------
// segk: expand CSR -> per-row group id.
__global__ void segk(const int* __restrict__ csr, int* __restrict__ seg) {
    int g = blockIdx.x * 256 + threadIdx.x;
    if (g >= NGRP) return;
    int p0 = csr[g], p1 = csr[g + 1];
    for (int r = p0; r < p1; ++r) seg[r] = g;
}

// ---------------------------------------------------------------------------
// s1_minmax: streaming per-group min/max. One wave per 64-row window, lane =
// column. Rows scanned serially with an 8-deep ping-pong register pipeline;
// every load is one coalesced 256 B request. Group boundaries are row-only ->
// wave-uniform flushes with coalesced 256 B stores.
// Flush destinations (race-free, no init needed; mirrored by s2_bias):
//   run starting at window row 0            -> head[window]
//   run ending at the window's last row     -> tail[window]
//   run strictly interior (one window owns) -> mnG/mxG[group]
__global__ __launch_bounds__(256, 6)
void s1_minmax(const float* __restrict__ x, const int* __restrict__ seg,
               float* __restrict__ mnG, float* __restrict__ mxG,
               float* __restrict__ hMn, float* __restrict__ hMx,
               float* __restrict__ tMn, float* __restrict__ tMx) {
    const int w = threadIdx.x >> 6, lane = threadIdx.x & 63;
    const int wid = blockIdx.x * 4 + w;           // window id
    if (wid >= NCHR) return;
    const int w0 = wid << 6;
    const int rows = min(64, NROWS - w0);         // 64, or 32 for the last
    const float* __restrict__ xc = x + (size_t)w0 * 64 + lane;
    const int segl = seg[min(w0 + lane, NROWS - 1)];   // row 'lane' group

    float vmn = INFINITY, vmx = -INFINITY;
    int gcur = __shfl(segl, 0);
    int runStart = 0;

    auto flushRun = [&](bool atEnd) {
        size_t ow = (size_t)wid * 64 + lane;
        if (runStart == 0)      { hMn[ow] = vmn; hMx[ow] = vmx; }
        else if (atEnd)         { tMn[ow] = vmn; tMx[ow] = vmx; }
        else { size_t og = (size_t)gcur * 64 + lane; mnG[og] = vmn; mxG[og] = vmx; }
    };

    float v[8], nv[8];
#define LD(buf, b)                                                          \
    _Pragma("unroll")                                                       \
    for (int j = 0; j < 8; ++j) buf[j] = xc[(size_t)((b) + j) * 64];
#define PROC(buf, b)                                                        \
    _Pragma("unroll")                                                       \
    for (int j = 0; j < 8; ++j) {                                           \
        int g = __shfl(segl, (b) + j);                                      \
        if (g != gcur) {                                                    \
            flushRun(false);                                                \
            gcur = g; runStart = (b) + j; vmn = buf[j]; vmx = buf[j];       \
        } else { vmn = fminf(vmn, buf[j]); vmx = fmaxf(vmx, buf[j]); }      \
    }

    LD(v, 0);
    if (rows == 64) {
#pragma unroll
        for (int base = 0; base < 64; base += 16) {
            if (base + 8 < 64)  { LD(nv, base + 8); }
            PROC(v, base);
            if (base + 16 < 64) { LD(v, base + 16); }
            if (base + 8 < 64)  { PROC(nv, base + 8); }
        }
    } else {                                      // rows == 32 (last window)
#pragma unroll
        for (int base = 0; base < 32; base += 16) {
            if (base + 8 < 32)  { LD(nv, base + 8); }
            PROC(v, base);
            if (base + 16 < 32) { LD(v, base + 16); }
            if (base + 8 < 32)  { PROC(nv, base + 8); }
        }
    }
#undef LD
#undef PROC
    flushRun(true);                               // last run ends at window end
}

// ---------------------------------------------------------------------------
// s2_bias: per 16 groups, merge the group's min/max contributions
// (head/tail/interior per s1's rule) into LDS, then the verified A2 MFMA
// (bf16 hi/lo split ~ fp32) -> biasG.
// Layouts: A[m=lane&15][k=q*8+j], C/D[row=q*4+reg][col=lane&15].
__global__ __launch_bounds__(256, 6)
void s2_bias(const int* __restrict__ csr,
             const float* __restrict__ mnG, const float* __restrict__ mxG,
             const float* __restrict__ hMn, const float* __restrict__ hMx,
             const float* __restrict__ tMn, const float* __restrict__ tMx,
             const unsigned short* __restrict__ wbh,
             const unsigned short* __restrict__ wbl,
             float* __restrict__ biasG) {
    __shared__ float mnF[GPB * 132];
    __shared__ int csrl[GPB + 1];

    const int tid = threadIdx.x, w = tid >> 6, lane = tid & 63;
    const int q = lane >> 4, nl = lane & 15;
    const int n = w * 16 + nl;
    const int g0 = blockIdx.x * GPB;

    if (tid <= GPB) csrl[tid] = csr[g0 + tid];
    __syncthreads();

    // gather: thread t -> group gl = t>>4, cols 4*(t&15)..+3
    {
        const int gl = tid >> 4, cq = tid & 15;
        const int gg = g0 + gl;
        const int s = csrl[gl], e = csrl[gl + 1];
        float4 mn = { INFINITY, INFINITY, INFINITY, INFINITY };
        float4 mx = { -INFINITY, -INFINITY, -INFINITY, -INFINITY };
        if (s < e) {
            const int wis = s >> 6, wie = (e - 1) >> 6;
            const int weS = min((wis << 6) + 64, NROWS);
            if (wis == wie && s != (wis << 6) && e != weS) {
                // strictly interior to one window -> direct slot
                mn = ((const float4*)(mnG + (size_t)gg * 64))[cq];
                mx = ((const float4*)(mxG + (size_t)gg * 64))[cq];
            } else {
                for (int wi = wis; wi <= wie; ++wi) {
                    const int ws_ = wi << 6;
                    const int we_ = min(ws_ + 64, NROWS);
                    const int a = max(s, ws_), b = min(e, we_);
                    const float4 *pm, *px;
                    if (a == ws_) {
                        pm = (const float4*)(hMn + (size_t)wi * 64) + cq;
                        px = (const float4*)(hMx + (size_t)wi * 64) + cq;
                    } else if (b == we_) {
                        pm = (const float4*)(tMn + (size_t)wi * 64) + cq;
                        px = (const float4*)(tMx + (size_t)wi * 64) + cq;
                    } else {
                        pm = (const float4*)(mnG + (size_t)gg * 64) + cq;
                        px = (const float4*)(mxG + (size_t)gg * 64) + cq;
                    }
                    mn = min4(mn, *pm);
                    mx = max4(mx, *px);
                }
            }
        }
        *(float4*)&mnF[gl * 132 + cq * 4]      = mn;   // k 0..63  = mn
        *(float4*)&mnF[gl * 132 + 64 + cq * 4] = mx;   // k 64..127 = mx
    }
    __syncthreads();

    // A2: bias GEMM on MFMA (verified). K=128 ([mn;mx]); hi/lo split.
    {
        const bf16x8* bhv = (const bf16x8*)wbh;
        const bf16x8* blv = (const bf16x8*)wbl;
        f32x4 acc = { 0.f, 0.f, 0.f, 0.f };
#pragma unroll
        for (int ks = 0; ks < 4; ++ks) {
            bf16x8 Bh = bhv[(ks * 64 + n) * 4 + q];
            bf16x8 Bl = blv[(ks * 64 + n) * 4 + q];
            const float* ap = &mnF[nl * 132 + ks * 32 + q * 8];
            f32x4 v0 = *(const f32x4*)ap;
            f32x4 v1 = *(const f32x4*)(ap + 4);
            union U { bf16x8 v; uint32 u[4]; } ah, al;
            ah.u[0] = pkbf(v0[0], v0[1]);
            ah.u[1] = pkbf(v0[2], v0[3]);
            ah.u[2] = pkbf(v1[0], v1[1]);
            ah.u[3] = pkbf(v1[2], v1[3]);
            float r0 = v0[0] - __uint_as_float(ah.u[0] << 16);
            float r1 = v0[1] - __uint_as_float(ah.u[0] & 0xffff0000u);
            float r2 = v0[2] - __uint_as_float(ah.u[1] << 16);
            float r3 = v0[3] - __uint_as_float(ah.u[1] & 0xffff0000u);
            float r4 = v1[0] - __uint_as_float(ah.u[2] << 16);
            float r5 = v1[1] - __uint_as_float(ah.u[2] & 0xffff0000u);
            float r6 = v1[2] - __uint_as_float(ah.u[3] << 16);
            float r7 = v1[3] - __uint_as_float(ah.u[3] & 0xffff0000u);
            al.u[0] = pkbf(r0, r1);
            al.u[1] = pkbf(r2, r3);
            al.u[2] = pkbf(r4, r5);
            al.u[3] = pkbf(r6, r7);
            acc = __builtin_amdgcn_mfma_f32_16x16x32_bf16(ah.v, Bh, acc, 0, 0, 0);
            acc = __builtin_amdgcn_mfma_f32_16x16x32_bf16(al.v, Bh, acc, 0, 0, 0);
            acc = __builtin_amdgcn_mfma_f32_16x16x32_bf16(ah.v, Bl, acc, 0, 0, 0);
        }
#pragma unroll
        for (int r = 0; r < 4; ++r)
            biasG[(size_t)(g0 + q * 4 + r) * 64 + n] = -acc[r];
    }
}

// ===========================================================================
// Fallback stats kernel (R3/R5-verified): used only if workspace is small.
// ===========================================================================
__device__ __forceinline__ void phase1_chunk(
        int gc, const float* __restrict__ x, const int* __restrict__ csr,
        const unsigned short* __restrict__ wbh,
        const unsigned short* __restrict__ wbl,
        float* __restrict__ biasG, int* __restrict__ seg,
        float* mnF, int* csrl,
        int tid, int w, int q, int nl, int n) {
    const int g0 = gc * GPB;
    if (tid <= GPB) csrl[tid] = csr[g0 + tid];
    __syncthreads();
    const int p0 = csrl[0], p1 = csrl[GPB];
    const float4* xr = (const float4*)x;
    for (int r = p0 + tid; r < p1; r += 256) {
        int lo = 0, hi = GPB;
#pragma unroll
        for (int it = 0; it < 5; ++it) {
            int mid = (lo + hi) >> 1;
            bool cb = csrl[mid] <= r;
            lo = cb ? mid : lo;
            hi = cb ? hi : mid;
        }
        seg[r] = g0 + lo;
    }
    {
        const int sub = q;
        auto redgrp = [&](int gl, int q0, int cnt,
                          float4 r0, float4 r1, float4 r2, float4 r3) {
            if (cnt <= 0) return;
            float4 mn = min4(min4(r0, r1), min4(r2, r3));
            float4 mx = max4(max4(r0, r1), max4(r2, r3));
            for (int i = 16; i < cnt; i += 16) {
                int ra = q0 + min(i + sub,      cnt - 1);
                int rb = q0 + min(i + sub + 4,  cnt - 1);
                int rc = q0 + min(i + sub + 8,  cnt - 1);
                int rd = q0 + min(i + sub + 12, cnt - 1);
                float4 a = xr[ra * 16 + nl], b = xr[rb * 16 + nl];
                float4 c = xr[rc * 16 + nl], d = xr[rd * 16 + nl];
                mn = min4(mn, min4(min4(a, b), min4(c, d)));
                mx = max4(mx, max4(max4(a, b), max4(c, d)));
            }
#pragma unroll
            for (int mk = 16; mk <= 32; mk <<= 1) {
                mn.x = fminf(mn.x, __shfl_xor(mn.x, mk));
                mn.y = fminf(mn.y, __shfl_xor(mn.y, mk));
                mn.z = fminf(mn.z, __shfl_xor(mn.z, mk));
                mn.w = fminf(mn.w, __shfl_xor(mn.w, mk));
                mx.x = fmaxf(mx.x, __shfl_xor(mx.x, mk));
                mx.y = fmaxf(mx.y, __shfl_xor(mx.y, mk));
                mx.z = fmaxf(mx.z, __shfl_xor(mx.z, mk));
                mx.w = fmaxf(mx.w, __shfl_xor(mx.w, mk));
            }
            if (sub == 0) {
                *(float4*)&mnF[gl * 132 + nl * 4]      = mn;
                *(float4*)&mnF[gl * 132 + 64 + nl * 4] = mx;
            }
        };
#pragma unroll
        for (int pr = 0; pr < 2; ++pr) {
            const int gA = w + pr * 8, gB = gA + 4;
            int qA = csrl[gA], cA = csrl[gA + 1] - qA;
            int qB = csrl[gB], cB = csrl[gB + 1] - qB;
            const int bA = (cA > 0) ? qA : 0, iA = max(cA - 1, 0);
            const int bB = (cB > 0) ? qB : 0, iB = max(cB - 1, 0);
            float4 a0 = xr[(bA + min(sub,      iA)) * 16 + nl];
            float4 a1 = xr[(bA + min(sub + 4,  iA)) * 16 + nl];
            float4 a2 = xr[(bA + min(sub + 8,  iA)) * 16 + nl];
            float4 a3 = xr[(bA + min(sub + 12, iA)) * 16 + nl];
            float4 b0 = xr[(bB + min(sub,      iB)) * 16 + nl];
            float4 b1 = xr[(bB + min(sub + 4,  iB)) * 16 + nl];
            float4 b2 = xr[(bB + min(sub + 8,  iB)) * 16 + nl];
            float4 b3 = xr[(bB + min(sub + 12, iB)) * 16 + nl];
            redgrp(gA, qA, cA, a0, a1, a2, a3);
            redgrp(gB, qB, cB, b0, b1, b2, b3);
        }
    }
    __syncthreads();
    {
        const bf16x8* bhv = (const bf16x8*)wbh;
        const bf16x8* blv = (const bf16x8*)wbl;
        f32x4 acc = { 0.f, 0.f, 0.f, 0.f };
#pragma unroll
        for (int ks = 0; ks < 4; ++ks) {
            bf16x8 Bh = bhv[(ks * 64 + n) * 4 + q];
            bf16x8 Bl = blv[(ks * 64 + n) * 4 + q];
            const float* ap = &mnF[nl * 132 + ks * 32 + q * 8];
            f32x4 v0 = *(const f32x4*)ap;
            f32x4 v1 = *(const f32x4*)(ap + 4);
            union U { bf16x8 v; uint32 u[4]; } ah, al;
            ah.u[0] = pkbf(v0[0], v0[1]);
            ah.u[1] = pkbf(v0[2], v0[3]);
            ah.u[2] = pkbf(v1[0], v1[1]);
            ah.u[3] = pkbf(v1[2], v1[3]);
            float r0 = v0[0] - __uint_as_float(ah.u[0] << 16);
            float r1 = v0[1] - __uint_as_float(ah.u[0] & 0xffff0000u);
            float r2 = v0[2] - __uint_as_float(ah.u[1] << 16);
            float r3 = v0[3] - __uint_as_float(ah.u[1] & 0xffff0000u);
            float r4 = v1[0] - __uint_as_float(ah.u[2] << 16);
            float r5 = v1[1] - __uint_as_float(ah.u[2] & 0xffff0000u);
            float r6 = v1[2] - __uint_as_float(ah.u[3] << 16);
            float r7 = v1[3] - __uint_as_float(ah.u[3] & 0xffff0000u);
            al.u[0] = pkbf(r0, r1);
            al.u[1] = pkbf(r2, r3);
            al.u[2] = pkbf(r4, r5);
            al.u[3] = pkbf(r6, r7);
            acc = __builtin_amdgcn_mfma_f32_16x16x32_bf16(ah.v, Bh, acc, 0, 0, 0);
            acc = __builtin_amdgcn_mfma_f32_16x16x32_bf16(al.v, Bh, acc, 0, 0, 0);
            acc = __builtin_amdgcn_mfma_f32_16x16x32_bf16(ah.v, Bl, acc, 0, 0, 0);
        }
#pragma unroll
        for (int r = 0; r < 4; ++r)
            biasG[(size_t)(g0 + q * 4 + r) * 64 + n] = -acc[r];
    }
}

__global__ __launch_bounds__(256, 6)
void grpstat(const float* __restrict__ x, const int* __restrict__ csr,
             const unsigned short* __restrict__ wbh,
             const unsigned short* __restrict__ wbl,
             float* __restrict__ biasG, int* __restrict__ seg) {
    __shared__ __align__(16) float mnF[GPB * 132];
    __shared__ int csrl[GPB + 1];
    const int tid = threadIdx.x, w = tid >> 6, lane = tid & 63;
    const int q = lane >> 4, nl = lane & 15;
    const int n = w * 16 + nl;
    phase1_chunk(blockIdx.x, x, csr, wbh, wbl, biasG, seg, mnF, csrl,
                 tid, w, q, nl, n);
}

// ---------------------------------------------------------------------------
// mlp: R3 version (one-shot 64-row blocks, verified fastest variant).
// Layouts: A[m=lane&15][k=q*8+j], C/D[row=q*4+reg][col=lane&15].
__global__ __launch_bounds__(256, 6)
void mlp(const float* __restrict__ x, const int* __restrict__ seg,
         const float* __restrict__ biasG,
         const unsigned short* __restrict__ wsf,
         const unsigned short* __restrict__ w2f,
         float* __restrict__ out) {
    __shared__ __align__(16) short xb[64 * 72];
    __shared__ __align__(16) short y1s[64 * 72];
    __shared__ __align__(16) int rowgrpL[64];

    const int tid = threadIdx.x, w = tid >> 6, lane = tid & 63;
    const int q = lane >> 4, nl = lane & 15;
    const int n = w * 16 + nl;

    const int r0 = blockIdx.x * 64;
    const int rows = min(64, NROWS - r0);
    const int availf = rows * 64;

    const float4* x4 = (const float4*)(x + (size_t)r0 * 64);
#pragma unroll
    for (int i = 0; i < 4; ++i) {
        int f = (i * 256 + tid) * 4;
        if (f < availf) {
            float4 v = x4[f >> 2];
            int r = f >> 6, c = f & 63;
            uint2 p;
            p.x = pkbf(v.x, v.y);
            p.y = pkbf(v.z, v.w);
            *(uint2*)(&xb[r * 72 + c]) = p;
        }
    }
    if (tid < 64) rowgrpL[tid] = seg[min(r0 + tid, NROWS - 1)];

    const bf16x8* wsv = (const bf16x8*)wsf;
    const bf16x8* w2v = (const bf16x8*)w2f;
    bf16x8 B0 = wsv[n * 4 + q];
    bf16x8 B1 = wsv[(64 + n) * 4 + q];
    bf16x8 C0 = w2v[n * 4 + q];
    bf16x8 C1 = w2v[(64 + n) * 4 + q];
    __syncthreads();   // barrier 1: xb + rowgrpL ready

    f32x4 h[4];
#pragma unroll
    for (int mt = 0; mt < 4; ++mt) {
        int rbase = mt * 16 + q * 4;
        int4 grp = *(const int4*)(&rowgrpL[rbase]);
        f32x4 acc;
        acc.x = biasG[(size_t)grp.x * 64 + n];
        acc.y = biasG[(size_t)grp.y * 64 + n];
        acc.z = biasG[(size_t)grp.z * 64 + n];
        acc.w = biasG[(size_t)grp.w * 64 + n];
        bf16x8 a0 = *(const bf16x8*)(&xb[(mt * 16 + nl) * 72 + q * 8]);
        bf16x8 a1 = *(const bf16x8*)(&xb[(mt * 16 + nl) * 72 + 32 + q * 8]);
        acc = __builtin_amdgcn_mfma_f32_16x16x32_bf16(a0, B0, acc, 0, 0, 0);
        acc = __builtin_amdgcn_mfma_f32_16x16x32_bf16(a1, B1, acc, 0, 0, 0);
        h[mt] = acc;
    }
#pragma unroll
    for (int mt = 0; mt < 4; ++mt) {
        int rbase = mt * 16 + q * 4;
        uint32 p01 = pkbf(leaky(h[mt][0]), leaky(h[mt][1]));
        uint32 p23 = pkbf(leaky(h[mt][2]), leaky(h[mt][3]));
        y1s[(rbase + 0) * 72 + n] = (short)(p01 & 0xffffu);
        y1s[(rbase + 1) * 72 + n] = (short)(p01 >> 16);
        y1s[(rbase + 2) * 72 + n] = (short)(p23 & 0xffffu);
        y1s[(rbase + 3) * 72 + n] = (short)(p23 >> 16);
    }
    __syncthreads();   // barrier 2: y1 ready

#pragma unroll
    for (int mt = 0; mt < 4; ++mt) {
        f32x4 acc = {0.f, 0.f, 0.f, 0.f};
        bf16x8 a0 = *(const bf16x8*)(&y1s[(mt * 16 + nl) * 72 + q * 8]);
        bf16x8 a1 = *(const bf16x8*)(&y1s[(mt * 16 + nl) * 72 + 32 + q * 8]);
        acc = __builtin_amdgcn_mfma_f32_16x16x32_bf16(a0, C0, acc, 0, 0, 0);
        acc = __builtin_amdgcn_mfma_f32_16x16x32_bf16(a1, C1, acc, 0, 0, 0);
        int rbase = mt * 16 + q * 4;
#pragma unroll
        for (int r = 0; r < 4; ++r) {
            int rl = rbase + r;
            if (rl < rows)
                out[(size_t)(r0 + rl) * 64 + n] = leaky(acc[r]);
        }
    }
}

// ---------------------------------------------------------------------------
extern "C" void kernel_launch(void* const* d_in, const int* in_sizes, int n_in,
                              void* d_out, int out_size, void* d_ws, size_t ws_size,
                              hipStream_t stream) {
    const float* x   = (const float*)d_in[0];
    const int*   csr = (const int*)d_in[1];
    const float* w1  = (const float*)d_in[2];
    const float* w2  = (const float*)d_in[3];
    float* out = (float*)d_out;

    char* base = (char*)d_ws;
    unsigned short* wsf = (unsigned short*)base;            // 8 KB
    unsigned short* w2f = (unsigned short*)(base + 8192);   // 8 KB
    unsigned short* wbh = (unsigned short*)(base + 16384);  // 16 KB
    unsigned short* wbl = (unsigned short*)(base + 32768);  // 16 KB
    float* biasG = (float*)(base + 49152);                  // 12.8 MB
    int*   seg   = (int*)(base + 49152 + 12800000);         // 2.0 MB
    // streaming-stats scratch
    float* mnG = (float*)(base + 14849152);                 // 12.8 MB
    float* mxG = (float*)(base + 27649152);                 // 12.8 MB
    float* hMn = (float*)(base + 40449152);                 // 2.0 MB
    float* hMx = (float*)(base + 42449280);                 // 2.0 MB
    float* tMn = (float*)(base + 44449408);                 // 2.0 MB
    float* tMx = (float*)(base + 46449536);                 // 2.0 MB
    const size_t need = 48449664ull;

    k0_frag<<<32, 256, 0, stream>>>(w1, w2, wsf, w2f, wbh, wbl);

    if (ws_size >= need) {
        segk<<<(NGRP + 255) / 256, 256, 0, stream>>>(csr, seg);
        s1_minmax<<<(NCHR + 3) / 4, 256, 0, stream>>>(x, seg, mnG, mxG,
                                                      hMn, hMx, tMn, tMx);
        s2_bias<<<NCHG, 256, 0, stream>>>(csr, mnG, mxG, hMn, hMx, tMn, tMx,
                                          wbh, wbl, biasG);
    } else {
        grpstat<<<NCHG, 256, 0, stream>>>(x, csr, wbh, wbl, biasG, seg);
    }
    mlp<<<NCHR, 256, 0, stream>>>(x, seg, biasG, wsf, w2f, out);
}